// Round 5
// baseline (248.113 us; speedup 1.0000x reference)
//
#include <hip/hip_runtime.h>
#include <hip/hip_bf16.h>
#include <math.h>

#define T_STEPS 64
#define BATCH   256
#define NX      512
#define NH      512

typedef short bf16x8 __attribute__((ext_vector_type(8)));
typedef float f32x4  __attribute__((ext_vector_type(4)));

// ---------------------------------------------------------------------------
// Kernel 1: P[r][h] = b1[h] + sum_k X[r][k] * W1[h][k]   (bf16 MFMA, f32 acc)
//   Same structure as round 3 (verified correct); staging conversion now uses
//   v_cvt_pk_bf16_f32 (via __float22bfloat162_rn) instead of 4-ALU bit trick.
// ---------------------------------------------------------------------------
__global__ __launch_bounds__(256, 2) void gemm_bf16_kernel(
    const float* __restrict__ X,    // [16384][512]
    const float* __restrict__ W1,   // [512][512]
    const float* __restrict__ b1,   // [512]
    float* __restrict__ P)          // [16384][512]
{
    __shared__ unsigned short lds[16384];   // 32 KB: A = [0,8192), B = [8192,16384)

    const int tid  = threadIdx.x;
    const int lane = tid & 63;
    const int wave = tid >> 6;
    const int wm   = wave >> 1;
    const int wn   = wave & 1;
    const int rbase = blockIdx.x * 128;
    const int nbase = blockIdx.y * 128;

    f32x4 acc[4][4] = {};

    for (int kb = 0; kb < 512; kb += 64) {
#pragma unroll
        for (int i = 0; i < 8; ++i) {
            int g   = tid + (i & 3) * 256;
            int ks  = g >> 9;
            int ms  = (g >> 6) & 7;
            int l   = g & 63;
            int row = ms * 16 + (l & 15);
            int kof = kb + ks * 32 + (l >> 4) * 8;
            const float* src = (i < 4) ? &X[(size_t)(rbase + row) * 512 + kof]
                                       : &W1[(size_t)(nbase + row) * 512 + kof];
            float4 v0 = *(const float4*)src;
            float4 v1 = *(const float4*)(src + 4);
            union { __hip_bfloat162 q[4]; int4 pk; } u;
            u.q[0] = __float22bfloat162_rn(make_float2(v0.x, v0.y));
            u.q[1] = __float22bfloat162_rn(make_float2(v0.z, v0.w));
            u.q[2] = __float22bfloat162_rn(make_float2(v1.x, v1.y));
            u.q[3] = __float22bfloat162_rn(make_float2(v1.z, v1.w));
            *(int4*)&lds[((i < 4) ? 0 : 8192) + g * 8] = u.pk;
        }
        __syncthreads();

#pragma unroll
        for (int ks = 0; ks < 2; ++ks) {
            bf16x8 afr[4], bfr[4];
#pragma unroll
            for (int mf = 0; mf < 4; ++mf)
                afr[mf] = *(const bf16x8*)&lds[((ks * 8 + wm * 4 + mf) * 64 + lane) * 8];
#pragma unroll
            for (int nf = 0; nf < 4; ++nf)
                bfr[nf] = *(const bf16x8*)&lds[8192 + ((ks * 8 + wn * 4 + nf) * 64 + lane) * 8];
#pragma unroll
            for (int mf = 0; mf < 4; ++mf)
#pragma unroll
                for (int nf = 0; nf < 4; ++nf)
                    acc[mf][nf] = __builtin_amdgcn_mfma_f32_16x16x32_bf16(
                        afr[mf], bfr[nf], acc[mf][nf], 0, 0, 0);
        }
        __syncthreads();
    }

    float bc[4];
#pragma unroll
    for (int nf = 0; nf < 4; ++nf)
        bc[nf] = b1[nbase + wn * 64 + nf * 16 + (lane & 15)];
#pragma unroll
    for (int mf = 0; mf < 4; ++mf) {
#pragma unroll
        for (int nf = 0; nf < 4; ++nf) {
#pragma unroll
            for (int r = 0; r < 4; ++r) {
                int m = rbase + wm * 64 + mf * 16 + ((lane >> 4) << 2) + r;
                int n = nbase + wn * 64 + nf * 16 + (lane & 15);
                P[(size_t)m * 512 + n] = acc[mf][nf][r] + bc[nf];
            }
        }
    }
}

// ---------------------------------------------------------------------------
// Kernel 2: per-batch Gram (unchanged from round 3 — verified correct)
// ---------------------------------------------------------------------------
__global__ __launch_bounds__(256) void gram_kernel(
    const float* __restrict__ X,    // [T][B][NX]
    float* __restrict__ Gt)         // [B][64][64]
{
    const int b   = blockIdx.x;
    const int tid = threadIdx.x;
    __shared__ float Xs[64][516];

    for (int idx = tid; idx < 64 * 128; idx += 256) {
        int t  = idx >> 7;
        int c4 = (idx & 127) << 2;
        *(float4*)&Xs[t][c4] = *(const float4*)&X[((size_t)t * BATCH + b) * NX + c4];
    }
    __syncthreads();

    const int a  = tid >> 4;
    const int bb = tid & 15;

    float acc[4][4] = {};
#pragma unroll 2
    for (int k = 0; k < 512; k += 4) {
        float4 sv[4], tv[4];
#pragma unroll
        for (int i = 0; i < 4; ++i) sv[i] = *(const float4*)&Xs[a * 4 + i][k];
#pragma unroll
        for (int j = 0; j < 4; ++j) tv[j] = *(const float4*)&Xs[bb + 16 * j][k];
#pragma unroll
        for (int i = 0; i < 4; ++i)
#pragma unroll
            for (int j = 0; j < 4; ++j)
                acc[i][j] += sv[i].x * tv[j].x + sv[i].y * tv[j].y
                           + sv[i].z * tv[j].z + sv[i].w * tv[j].w;
    }
#pragma unroll
    for (int j = 0; j < 4; ++j)
#pragma unroll
        for (int i = 0; i < 4; ++i)
            Gt[((size_t)b * 64 + (bb + 16 * j)) * 64 + (a * 4 + i)] = acc[i][j];
}

// ---------------------------------------------------------------------------
// 64-lane sum via DPP (VALU-only; replaces ds_bpermute-based __shfl chain).
// Result valid in lane 63.
// ---------------------------------------------------------------------------
__device__ __forceinline__ float dpp_sum64(float v) {
    v += __int_as_float(__builtin_amdgcn_update_dpp(0, __float_as_int(v), 0x111, 0xf, 0xf, true)); // row_shr:1
    v += __int_as_float(__builtin_amdgcn_update_dpp(0, __float_as_int(v), 0x112, 0xf, 0xf, true)); // row_shr:2
    v += __int_as_float(__builtin_amdgcn_update_dpp(0, __float_as_int(v), 0x114, 0xf, 0xf, true)); // row_shr:4
    v += __int_as_float(__builtin_amdgcn_update_dpp(0, __float_as_int(v), 0x118, 0xf, 0xf, true)); // row_shr:8
    v += __int_as_float(__builtin_amdgcn_update_dpp(0, __float_as_int(v), 0x142, 0xf, 0xf, true)); // row_bcast:15
    v += __int_as_float(__builtin_amdgcn_update_dpp(0, __float_as_int(v), 0x143, 0xf, 0xf, true)); // row_bcast:31
    return v;
}

// ---------------------------------------------------------------------------
// Kernel 3: scan — register history + LDS coeff (best of rounds 3 & 4).
//   One block per batch, 512 threads = one per hidden unit.
//   * FULL 64-step unroll; hreg[64] in registers, all indices static.
//   * coeff[s] = eta*lam^{t-1-s}*G[t][s] in LDS, double-buffered by parity,
//     written ONE step ahead by wave-0 threads from a G row prefetched TWO
//     steps ahead (kills round 3's per-step s_load stall chain).
//   * History reads: exactly ceil(t/4) uniform ds_read_b128 broadcasts per
//     step + t fmafs on register operands (zero LDS BW for history —
//     round 4's LDS-BW/latency problem gone).
//   * P prefetched TWO steps ahead (L3-latency cover).
//   * Wave reduce via DPP (VALU) instead of ds_bpermute shfl chain.
//   * ONE barrier per step; no LDS zero-init needed (every slot read is
//     written first: coeff[par][s], s<t, was written at step t-1; red[par]
//     written pre-barrier same step).
// ---------------------------------------------------------------------------
__global__ __launch_bounds__(512, 1) void scan_kernel(
    const float* __restrict__ P,    // [T][B][NH] (== outH, aliased; same-thread
    const float* __restrict__ Gt,   //  read-before-write per address)
    const float* __restrict__ w2,   // [NH][2]
    const float* __restrict__ b2,   // [2]
    const float* __restrict__ w21,  // [NH][2]
    const float* __restrict__ lamp,
    const float* __restrict__ etap,
    float* __restrict__ outH,       // [T][B][NH]
    float* __restrict__ outY)       // [T][B][2]
{
    const int b = blockIdx.x;
    const int h = threadIdx.x;

    __shared__ float coeff[2][64];
    __shared__ float red[2][16];

    const float eta = etap[0];
    const float lam = fminf(lamp[0], 1.0f);
    const float2 w21v = *(const float2*)&w21[2 * h];
    const float2 w2v  = *(const float2*)&w2[2 * h];
    const float b20 = b2[0], b21 = b2[1];
    const float* gb  = Gt + (size_t)b * 4096;
    const float* Pb  = P + (size_t)b * NH + h;
    float*       oHb = outH + (size_t)b * NH + h;

    float hreg[64];
    float pv    = Pb[0];
    float pv_n1 = Pb[(size_t)BATCH * NH];
    float pv_n2 = 0.f;
    float g_cur = (h < 64) ? gb[64 + h] : 0.f;   // G[1][h]
    float g_nxt = 0.f;
    float pw  = 1.0f;                            // lam^(t-h), valid from t==h
    float a2x = 0.f, a2y = 0.f;

#pragma unroll
    for (int t = 0; t < T_STEPS; ++t) {
        const int par = t & 1;

        // prefetches for step t+2 (consumed via rotation below)
        if (t < 62) {
            pv_n2 = Pb[(size_t)(t + 2) * (BATCH * NH)];
            if (h < 64) g_nxt = gb[(t + 2) * 64 + h];
        }

        // history term: sum_{s<t} coeff[par][s] * hreg[s]
        float ac0 = 0.f, ac1 = 0.f, ac2 = 0.f, ac3 = 0.f;
#pragma unroll
        for (int i = 0; i < (t >> 2); ++i) {
            float4 cf = *(const float4*)&coeff[par][i * 4];
            ac0 = fmaf(cf.x, hreg[i * 4 + 0], ac0);
            ac1 = fmaf(cf.y, hreg[i * 4 + 1], ac1);
            ac2 = fmaf(cf.z, hreg[i * 4 + 2], ac2);
            ac3 = fmaf(cf.w, hreg[i * 4 + 3], ac3);
        }
        if (t & 3) {  // static remainder (t compile-time after unroll)
            float4 cf = *(const float4*)&coeff[par][(t >> 2) * 4];
            if ((t & 3) >= 1) ac0 = fmaf(cf.x, hreg[(t >> 2) * 4 + 0], ac0);
            if ((t & 3) >= 2) ac1 = fmaf(cf.y, hreg[(t >> 2) * 4 + 1], ac1);
            if ((t & 3) >= 3) ac2 = fmaf(cf.z, hreg[(t >> 2) * 4 + 2], ac2);
        }

        float a1 = pv + w21v.x * a2x + w21v.y * a2y + ((ac0 + ac1) + (ac2 + ac3));
        float hv = 1.0f / (1.0f + __expf(-a1));

        hreg[t] = hv;                                   // static index
        oHb[(size_t)t * (BATCH * NH)] = hv;

        // wave-level reduce of (hv*w2) via DPP; lane 63 holds wave sum
        float p0 = dpp_sum64(hv * w2v.x);
        float p1 = dpp_sum64(hv * w2v.y);
        if ((h & 63) == 63) {
            red[par][(h >> 6) * 2]     = p0;
            red[par][(h >> 6) * 2 + 1] = p1;
        }

        // write next step's coeff (G row prefetched 2 steps ago)
        if (t < 63 && h < 64 && h <= t) {
            coeff[par ^ 1][h] = eta * pw * g_cur;
            pw *= lam;
        }

        __syncthreads();

        // finish a2 for step t+1 (uniform LDS broadcasts)
        float4 r0 = *(const float4*)&red[par][0];
        float4 r1 = *(const float4*)&red[par][4];
        float4 r2 = *(const float4*)&red[par][8];
        float4 r3 = *(const float4*)&red[par][12];
        float s0 = b20 + ((r0.x + r0.z) + (r1.x + r1.z)) + ((r2.x + r2.z) + (r3.x + r3.z));
        float s1 = b21 + ((r0.y + r0.w) + (r1.y + r1.w)) + ((r2.y + r2.w) + (r3.y + r3.w));
        if (h == 0) {
            outY[((size_t)t * BATCH + b) * 2 + 0] = 1.0f / (1.0f + __expf(-s0));
            outY[((size_t)t * BATCH + b) * 2 + 1] = 1.0f / (1.0f + __expf(-s1));
        }
        a2x = s0; a2y = s1;
        pv = pv_n1; pv_n1 = pv_n2;
        g_cur = g_nxt;
    }
}

// ---------------------------------------------------------------------------
extern "C" void kernel_launch(void* const* d_in, const int* in_sizes, int n_in,
                              void* d_out, int out_size, void* d_ws, size_t ws_size,
                              hipStream_t stream) {
    const float* x   = (const float*)d_in[0];
    const float* w1  = (const float*)d_in[1];
    const float* b1  = (const float*)d_in[2];
    const float* w2  = (const float*)d_in[3];
    const float* b2  = (const float*)d_in[4];
    const float* w21 = (const float*)d_in[5];
    const float* lam = (const float*)d_in[6];
    const float* eta = (const float*)d_in[7];

    float* outH = (float*)d_out;                       // [64*256*512], doubles as P
    float* outY = outH + (size_t)T_STEPS * BATCH * NH; // [64*256*2]
    float* Gt   = (float*)d_ws;                        // [256*64*64] = 4 MB

    gemm_bf16_kernel<<<dim3(128, 4), 256, 0, stream>>>(x, w1, b1, outH);
    gram_kernel<<<256, 256, 0, stream>>>(x, Gt);
    scan_kernel<<<256, 512, 0, stream>>>(outH, Gt, w2, b2, w21, lam, eta, outH, outY);
}

// Round 7
// 117.968 us; speedup vs baseline: 2.1032x; 2.1032x over previous
//
#include <hip/hip_runtime.h>
#include <hip/hip_bf16.h>
#include <math.h>

#define T_STEPS 64
#define BATCH   256
#define NX      512
#define NH      512

typedef short bf16x8 __attribute__((ext_vector_type(8)));
typedef float f32x4  __attribute__((ext_vector_type(4)));

// ---------------------------------------------------------------------------
// Kernel 1: P[r][h] = b1[h] + sum_k X[r][k] * W1[h][k]   (bf16 MFMA, f32 acc)
//   (unchanged — verified rounds 3-5)
// ---------------------------------------------------------------------------
__global__ __launch_bounds__(256, 2) void gemm_bf16_kernel(
    const float* __restrict__ X,    // [16384][512]
    const float* __restrict__ W1,   // [512][512]
    const float* __restrict__ b1,   // [512]
    float* __restrict__ P)          // [16384][512]
{
    __shared__ unsigned short lds[16384];   // 32 KB: A = [0,8192), B = [8192,16384)

    const int tid  = threadIdx.x;
    const int lane = tid & 63;
    const int wave = tid >> 6;
    const int wm   = wave >> 1;
    const int wn   = wave & 1;
    const int rbase = blockIdx.x * 128;
    const int nbase = blockIdx.y * 128;

    f32x4 acc[4][4] = {};

    for (int kb = 0; kb < 512; kb += 64) {
#pragma unroll
        for (int i = 0; i < 8; ++i) {
            int g   = tid + (i & 3) * 256;
            int ks  = g >> 9;
            int ms  = (g >> 6) & 7;
            int l   = g & 63;
            int row = ms * 16 + (l & 15);
            int kof = kb + ks * 32 + (l >> 4) * 8;
            const float* src = (i < 4) ? &X[(size_t)(rbase + row) * 512 + kof]
                                       : &W1[(size_t)(nbase + row) * 512 + kof];
            float4 v0 = *(const float4*)src;
            float4 v1 = *(const float4*)(src + 4);
            union { __hip_bfloat162 q[4]; int4 pk; } u;
            u.q[0] = __float22bfloat162_rn(make_float2(v0.x, v0.y));
            u.q[1] = __float22bfloat162_rn(make_float2(v0.z, v0.w));
            u.q[2] = __float22bfloat162_rn(make_float2(v1.x, v1.y));
            u.q[3] = __float22bfloat162_rn(make_float2(v1.z, v1.w));
            *(int4*)&lds[((i < 4) ? 0 : 8192) + g * 8] = u.pk;
        }
        __syncthreads();

#pragma unroll
        for (int ks = 0; ks < 2; ++ks) {
            bf16x8 afr[4], bfr[4];
#pragma unroll
            for (int mf = 0; mf < 4; ++mf)
                afr[mf] = *(const bf16x8*)&lds[((ks * 8 + wm * 4 + mf) * 64 + lane) * 8];
#pragma unroll
            for (int nf = 0; nf < 4; ++nf)
                bfr[nf] = *(const bf16x8*)&lds[8192 + ((ks * 8 + wn * 4 + nf) * 64 + lane) * 8];
#pragma unroll
            for (int mf = 0; mf < 4; ++mf)
#pragma unroll
                for (int nf = 0; nf < 4; ++nf)
                    acc[mf][nf] = __builtin_amdgcn_mfma_f32_16x16x32_bf16(
                        afr[mf], bfr[nf], acc[mf][nf], 0, 0, 0);
        }
        __syncthreads();
    }

    float bc[4];
#pragma unroll
    for (int nf = 0; nf < 4; ++nf)
        bc[nf] = b1[nbase + wn * 64 + nf * 16 + (lane & 15)];
#pragma unroll
    for (int mf = 0; mf < 4; ++mf) {
#pragma unroll
        for (int nf = 0; nf < 4; ++nf) {
#pragma unroll
            for (int r = 0; r < 4; ++r) {
                int m = rbase + wm * 64 + mf * 16 + ((lane >> 4) << 2) + r;
                int n = nbase + wn * 64 + nf * 16 + (lane & 15);
                P[(size_t)m * 512 + n] = acc[mf][nf][r] + bc[nf];
            }
        }
    }
}

// ---------------------------------------------------------------------------
// Kernel 2: per-batch Gram (unchanged — verified rounds 3-5)
// ---------------------------------------------------------------------------
__global__ __launch_bounds__(256) void gram_kernel(
    const float* __restrict__ X,    // [T][B][NX]
    float* __restrict__ Gt)         // [B][64][64]
{
    const int b   = blockIdx.x;
    const int tid = threadIdx.x;
    __shared__ float Xs[64][516];

    for (int idx = tid; idx < 64 * 128; idx += 256) {
        int t  = idx >> 7;
        int c4 = (idx & 127) << 2;
        *(float4*)&Xs[t][c4] = *(const float4*)&X[((size_t)t * BATCH + b) * NX + c4];
    }
    __syncthreads();

    const int a  = tid >> 4;
    const int bb = tid & 15;

    float acc[4][4] = {};
#pragma unroll 2
    for (int k = 0; k < 512; k += 4) {
        float4 sv[4], tv[4];
#pragma unroll
        for (int i = 0; i < 4; ++i) sv[i] = *(const float4*)&Xs[a * 4 + i][k];
#pragma unroll
        for (int j = 0; j < 4; ++j) tv[j] = *(const float4*)&Xs[bb + 16 * j][k];
#pragma unroll
        for (int i = 0; i < 4; ++i)
#pragma unroll
            for (int j = 0; j < 4; ++j)
                acc[i][j] += sv[i].x * tv[j].x + sv[i].y * tv[j].y
                           + sv[i].z * tv[j].z + sv[i].w * tv[j].w;
    }
#pragma unroll
    for (int j = 0; j < 4; ++j)
#pragma unroll
        for (int i = 0; i < 4; ++i)
            Gt[((size_t)b * 64 + (bb + 16 * j)) * 64 + (a * 4 + i)] = acc[i][j];
}

// ---------------------------------------------------------------------------
// 64-lane sum via DPP; result valid in lane 63. (HW-verified rounds 4-5)
// ---------------------------------------------------------------------------
__device__ __forceinline__ float dpp_sum64(float v) {
    v += __int_as_float(__builtin_amdgcn_update_dpp(0, __float_as_int(v), 0x111, 0xf, 0xf, true)); // row_shr:1
    v += __int_as_float(__builtin_amdgcn_update_dpp(0, __float_as_int(v), 0x112, 0xf, 0xf, true)); // row_shr:2
    v += __int_as_float(__builtin_amdgcn_update_dpp(0, __float_as_int(v), 0x114, 0xf, 0xf, true)); // row_shr:4
    v += __int_as_float(__builtin_amdgcn_update_dpp(0, __float_as_int(v), 0x118, 0xf, 0xf, true)); // row_shr:8
    v += __int_as_float(__builtin_amdgcn_update_dpp(0, __float_as_int(v), 0x142, 0xf, 0xf, true)); // row_bcast:15
    v += __int_as_float(__builtin_amdgcn_update_dpp(0, __float_as_int(v), 0x143, 0xf, 0xf, true)); // row_bcast:31
    return v;
}

// ---------------------------------------------------------------------------
// Kernel 3: scan — CHUNKED register/LDS hybrid (round 6 + lam_pow barrier fix).
//   4 chunks x 16 steps. Per chunk:
//     * C[16][64] = eta*lam^{t-1-s}*G[t][s] built cooperatively (uniform LDS
//       broadcasts thereafter; no scalar-load chains on the serial path).
//     * pvreg[16]: whole chunk's P preloaded (latency hidden by matmul;
//       same-thread read-before-overwrite keeps P/outH alias safe).
//     * macc[16] = sum_{s<t0} C[tt][s]*Hs[s][h] — past-chunk history matmul,
//       16 fmaf per 4B LDS read, fully parallel.
//     * 16-step #pragma unroll sequential loop: hcur[16] registers (static
//       indices only — rule #20), <=15 in-chunk history fmafs, DPP reduce,
//       parity-buffered red, ONE barrier per step.
//   Hs[64][512]: column h written/read only by thread h; lanes stride-1 ->
//   conflict-free. No LDS zero-init anywhere.
//   RACE FIX vs round 6: __syncthreads() after lam_pow init — waves 1-7 were
//   reading the table in chunk 0's C-build before wave 0 wrote it.
// ---------------------------------------------------------------------------
__global__ __launch_bounds__(512, 1) void scan_kernel(
    const float* __restrict__ P,    // [T][B][NH]  (== outH, aliased)
    const float* __restrict__ Gt,   // [B][64][64]
    const float* __restrict__ w2,   // [NH][2]
    const float* __restrict__ b2,   // [2]
    const float* __restrict__ w21,  // [NH][2]
    const float* __restrict__ lamp,
    const float* __restrict__ etap,
    float* __restrict__ outH,       // [T][B][NH]
    float* __restrict__ outY)       // [T][B][2]
{
    const int b = blockIdx.x;
    const int h = threadIdx.x;

    __shared__ float Hs[64][512];   // 128 KB history; col h private to thread h
    __shared__ float C[16][64];     // per-chunk coefficient matrix
    __shared__ float lam_pow[64];
    __shared__ float red[2][16];

    const float eta = etap[0];
    const float lam = fminf(lamp[0], 1.0f);
    const float2 w21v = *(const float2*)&w21[2 * h];
    const float2 w2v  = *(const float2*)&w2[2 * h];
    const float b20 = b2[0], b21 = b2[1];
    const float* gb  = Gt + (size_t)b * 4096;
    const float* Pb  = P + (size_t)b * NH + h;
    float*       oHb = outH + (size_t)b * NH + h;

    if (h < 64)
        lam_pow[h] = (h == 0) ? 1.0f : exp2f((float)h * log2f(lam));
    __syncthreads();   // FIX: order lam_pow writes before chunk-0 C-build reads

    float a2x = 0.f, a2y = 0.f;

    for (int c = 0; c < 4; ++c) {
        const int t0 = c * 16;

        // ---- build C cooperatively: 1024 entries, 2 per thread ----------
        // (prev chunk's C reads all precede its last per-step barrier; safe)
#pragma unroll
        for (int e = h; e < 1024; e += 512) {
            int tt = e >> 6, s = e & 63;
            int t  = t0 + tt;
            float cv = 0.f;
            if (s < t) cv = eta * lam_pow[t - 1 - s] * gb[t * 64 + s];
            C[tt][s] = cv;
        }
        __syncthreads();

        // ---- preload chunk's P (16 coalesced loads, covered by matmul) ---
        float pvreg[16];
#pragma unroll
        for (int tt = 0; tt < 16; ++tt)
            pvreg[tt] = Pb[(size_t)(t0 + tt) * (BATCH * NH)];

        // ---- past-chunk history matmul ----------------------------------
        float macc[16] = {};
#pragma unroll 2
        for (int s = 0; s < t0; ++s) {
            float hsv = Hs[s][h];
#pragma unroll
            for (int tt = 0; tt < 16; ++tt)
                macc[tt] = fmaf(C[tt][s], hsv, macc[tt]);
        }

        // ---- 16 sequential steps ----------------------------------------
        float hcur[16];
#pragma unroll
        for (int tt = 0; tt < 16; ++tt) {
            const int t   = t0 + tt;
            const int par = tt & 1;

            float a1 = pvreg[tt] + w21v.x * a2x + w21v.y * a2y + macc[tt];
#pragma unroll
            for (int j = 0; j < tt; ++j)
                a1 = fmaf(C[tt][t0 + j], hcur[j], a1);

            float hv = 1.0f / (1.0f + __expf(-a1));
            hcur[tt] = hv;
            Hs[t][h] = hv;
            oHb[(size_t)t * (BATCH * NH)] = hv;

            float p0 = dpp_sum64(hv * w2v.x);
            float p1 = dpp_sum64(hv * w2v.y);
            if ((h & 63) == 63) {
                red[par][(h >> 6) * 2]     = p0;
                red[par][(h >> 6) * 2 + 1] = p1;
            }
            __syncthreads();

            float4 r0 = *(const float4*)&red[par][0];
            float4 r1 = *(const float4*)&red[par][4];
            float4 r2 = *(const float4*)&red[par][8];
            float4 r3 = *(const float4*)&red[par][12];
            float s0 = b20 + ((r0.x + r0.z) + (r1.x + r1.z)) + ((r2.x + r2.z) + (r3.x + r3.z));
            float s1 = b21 + ((r0.y + r0.w) + (r1.y + r1.w)) + ((r2.y + r2.w) + (r3.y + r3.w));
            if (h == 0) {
                outY[((size_t)t * BATCH + b) * 2 + 0] = 1.0f / (1.0f + __expf(-s0));
                outY[((size_t)t * BATCH + b) * 2 + 1] = 1.0f / (1.0f + __expf(-s1));
            }
            a2x = s0; a2y = s1;
        }
    }
}

// ---------------------------------------------------------------------------
extern "C" void kernel_launch(void* const* d_in, const int* in_sizes, int n_in,
                              void* d_out, int out_size, void* d_ws, size_t ws_size,
                              hipStream_t stream) {
    const float* x   = (const float*)d_in[0];
    const float* w1  = (const float*)d_in[1];
    const float* b1  = (const float*)d_in[2];
    const float* w2  = (const float*)d_in[3];
    const float* b2  = (const float*)d_in[4];
    const float* w21 = (const float*)d_in[5];
    const float* lam = (const float*)d_in[6];
    const float* eta = (const float*)d_in[7];

    float* outH = (float*)d_out;                       // [64*256*512], doubles as P
    float* outY = outH + (size_t)T_STEPS * BATCH * NH; // [64*256*2]
    float* Gt   = (float*)d_ws;                        // [256*64*64] = 4 MB

    gemm_bf16_kernel<<<dim3(128, 4), 256, 0, stream>>>(x, w1, b1, outH);
    gram_kernel<<<256, 256, 0, stream>>>(x, Gt);
    scan_kernel<<<256, 512, 0, stream>>>(outH, Gt, w2, b2, w21, lam, eta, outH, outY);
}

// Round 8
// 95.975 us; speedup vs baseline: 2.5852x; 1.2292x over previous
//
#include <hip/hip_runtime.h>
#include <hip/hip_bf16.h>
#include <math.h>

#define T_STEPS 64
#define BATCH   256
#define NX      512
#define NH      512

typedef short bf16x8 __attribute__((ext_vector_type(8)));
typedef float f32x4  __attribute__((ext_vector_type(4)));

// ---------------------------------------------------------------------------
// Kernel 1: P[r][h] = b1[h] + sum_k X[r][k] * W1[h][k]   (bf16 MFMA, f32 acc)
//   Structure verified rounds 3-7. Only change: launch_bounds (256,2)->(256,4)
//   (VGPR=68, LDS=33KB permit 4 blocks/CU; more cross-block overlap hides
//   staging + barrier drains per m114).
// ---------------------------------------------------------------------------
__global__ __launch_bounds__(256, 4) void gemm_bf16_kernel(
    const float* __restrict__ X,    // [16384][512]
    const float* __restrict__ W1,   // [512][512]
    const float* __restrict__ b1,   // [512]
    float* __restrict__ P)          // [16384][512]
{
    __shared__ unsigned short lds[16384];   // 32 KB: A = [0,8192), B = [8192,16384)

    const int tid  = threadIdx.x;
    const int lane = tid & 63;
    const int wave = tid >> 6;
    const int wm   = wave >> 1;
    const int wn   = wave & 1;
    const int rbase = blockIdx.x * 128;
    const int nbase = blockIdx.y * 128;

    f32x4 acc[4][4] = {};

    for (int kb = 0; kb < 512; kb += 64) {
#pragma unroll
        for (int i = 0; i < 8; ++i) {
            int g   = tid + (i & 3) * 256;
            int ks  = g >> 9;
            int ms  = (g >> 6) & 7;
            int l   = g & 63;
            int row = ms * 16 + (l & 15);
            int kof = kb + ks * 32 + (l >> 4) * 8;
            const float* src = (i < 4) ? &X[(size_t)(rbase + row) * 512 + kof]
                                       : &W1[(size_t)(nbase + row) * 512 + kof];
            float4 v0 = *(const float4*)src;
            float4 v1 = *(const float4*)(src + 4);
            union { __hip_bfloat162 q[4]; int4 pk; } u;
            u.q[0] = __float22bfloat162_rn(make_float2(v0.x, v0.y));
            u.q[1] = __float22bfloat162_rn(make_float2(v0.z, v0.w));
            u.q[2] = __float22bfloat162_rn(make_float2(v1.x, v1.y));
            u.q[3] = __float22bfloat162_rn(make_float2(v1.z, v1.w));
            *(int4*)&lds[((i < 4) ? 0 : 8192) + g * 8] = u.pk;
        }
        __syncthreads();

#pragma unroll
        for (int ks = 0; ks < 2; ++ks) {
            bf16x8 afr[4], bfr[4];
#pragma unroll
            for (int mf = 0; mf < 4; ++mf)
                afr[mf] = *(const bf16x8*)&lds[((ks * 8 + wm * 4 + mf) * 64 + lane) * 8];
#pragma unroll
            for (int nf = 0; nf < 4; ++nf)
                bfr[nf] = *(const bf16x8*)&lds[8192 + ((ks * 8 + wn * 4 + nf) * 64 + lane) * 8];
#pragma unroll
            for (int mf = 0; mf < 4; ++mf)
#pragma unroll
                for (int nf = 0; nf < 4; ++nf)
                    acc[mf][nf] = __builtin_amdgcn_mfma_f32_16x16x32_bf16(
                        afr[mf], bfr[nf], acc[mf][nf], 0, 0, 0);
        }
        __syncthreads();
    }

    float bc[4];
#pragma unroll
    for (int nf = 0; nf < 4; ++nf)
        bc[nf] = b1[nbase + wn * 64 + nf * 16 + (lane & 15)];
#pragma unroll
    for (int mf = 0; mf < 4; ++mf) {
#pragma unroll
        for (int nf = 0; nf < 4; ++nf) {
#pragma unroll
            for (int r = 0; r < 4; ++r) {
                int m = rbase + wm * 64 + mf * 16 + ((lane >> 4) << 2) + r;
                int n = nbase + wn * 64 + nf * 16 + (lane & 15);
                P[(size_t)m * 512 + n] = acc[mf][nf][r] + bc[nf];
            }
        }
    }
}

// ---------------------------------------------------------------------------
// Kernel 2: per-batch Gram — REWRITTEN with MFMA.
//   G_b = X_b · X_b^T  (64x64, K=512), bf16 inputs, f32 accumulate.
//   Both MFMA operands use the IDENTICAL fragment gather (A-frag row = lane&15
//   = B-frag row in the verified gemm convention), so ONE fragment-ordered
//   LDS stage (64 KB bf16) serves both roles. 4 waves: wave w computes the
//   16-row strip mf=w against all 4 nf column groups = 64 MFMA/wave.
//   G is symmetric -> C/D row/col orientation is correctness-neutral.
//   bf16 error on G: ~0.05 abs on G~N(0,512); x eta ~ 5e-4 per coeff -> a1
//   error ~2e-3, well under the 2e-2 threshold.
// ---------------------------------------------------------------------------
__global__ __launch_bounds__(256) void gram_kernel(
    const float* __restrict__ X,    // [T][B][NX]
    float* __restrict__ Gt)         // [B][64][64]
{
    const int b    = blockIdx.x;
    const int tid  = threadIdx.x;
    const int lane = tid & 63;
    const int w    = tid >> 6;      // wave 0..3

    __shared__ unsigned short xs[4096 * 8];   // 64 KB, fragment order
    // group g = (ks*4 + ms)*64 + lane holds 8 bf16: row = ms*16+(lane&15),
    // k = ks*32 + (lane>>4)*8 .. +8   (ks in [0,16), ms in [0,4))

#pragma unroll
    for (int i = 0; i < 16; ++i) {
        int g   = tid + i * 256;          // 0..4095
        int ks  = g >> 8;
        int ms  = (g >> 6) & 3;
        int l   = g & 63;
        int row = ms * 16 + (l & 15);     // time index t in [0,64)
        int k   = ks * 32 + (l >> 4) * 8;
        const float* src = &X[(size_t)row * (BATCH * NX) + (size_t)b * NX + k];
        float4 v0 = *(const float4*)src;
        float4 v1 = *(const float4*)(src + 4);
        union { __hip_bfloat162 q[4]; int4 pk; } u;
        u.q[0] = __float22bfloat162_rn(make_float2(v0.x, v0.y));
        u.q[1] = __float22bfloat162_rn(make_float2(v0.z, v0.w));
        u.q[2] = __float22bfloat162_rn(make_float2(v1.x, v1.y));
        u.q[3] = __float22bfloat162_rn(make_float2(v1.z, v1.w));
        *(int4*)&xs[g * 8] = u.pk;
    }
    __syncthreads();

    f32x4 acc[4] = {};
#pragma unroll
    for (int ks = 0; ks < 16; ++ks) {
        bf16x8 afr = *(const bf16x8*)&xs[((ks * 4 + w) * 64 + lane) * 8];
#pragma unroll
        for (int nf = 0; nf < 4; ++nf) {
            bf16x8 bfr = *(const bf16x8*)&xs[((ks * 4 + nf) * 64 + lane) * 8];
            acc[nf] = __builtin_amdgcn_mfma_f32_16x16x32_bf16(afr, bfr, acc[nf], 0, 0, 0);
        }
    }

    // C/D map: col = lane&15, row = (lane>>4)*4 + r   (G symmetric)
#pragma unroll
    for (int nf = 0; nf < 4; ++nf) {
#pragma unroll
        for (int r = 0; r < 4; ++r) {
            int mrow = w * 16 + ((lane >> 4) << 2) + r;
            int ncol = nf * 16 + (lane & 15);
            Gt[((size_t)b * 64 + mrow) * 64 + ncol] = acc[nf][r];
        }
    }
}

// ---------------------------------------------------------------------------
// 64-lane sum via DPP; result valid in lane 63. (HW-verified rounds 4-7)
// ---------------------------------------------------------------------------
__device__ __forceinline__ float dpp_sum64(float v) {
    v += __int_as_float(__builtin_amdgcn_update_dpp(0, __float_as_int(v), 0x111, 0xf, 0xf, true)); // row_shr:1
    v += __int_as_float(__builtin_amdgcn_update_dpp(0, __float_as_int(v), 0x112, 0xf, 0xf, true)); // row_shr:2
    v += __int_as_float(__builtin_amdgcn_update_dpp(0, __float_as_int(v), 0x114, 0xf, 0xf, true)); // row_shr:4
    v += __int_as_float(__builtin_amdgcn_update_dpp(0, __float_as_int(v), 0x118, 0xf, 0xf, true)); // row_shr:8
    v += __int_as_float(__builtin_amdgcn_update_dpp(0, __float_as_int(v), 0x142, 0xf, 0xf, true)); // row_bcast:15
    v += __int_as_float(__builtin_amdgcn_update_dpp(0, __float_as_int(v), 0x143, 0xf, 0xf, true)); // row_bcast:31
    return v;
}

// ---------------------------------------------------------------------------
// Kernel 3: scan — CHUNKED register/LDS hybrid (unchanged from round 7,
// verified: 49.5 us, absmax at bf16 floor).
// ---------------------------------------------------------------------------
__global__ __launch_bounds__(512, 1) void scan_kernel(
    const float* __restrict__ P,    // [T][B][NH]  (== outH, aliased)
    const float* __restrict__ Gt,   // [B][64][64]
    const float* __restrict__ w2,   // [NH][2]
    const float* __restrict__ b2,   // [2]
    const float* __restrict__ w21,  // [NH][2]
    const float* __restrict__ lamp,
    const float* __restrict__ etap,
    float* __restrict__ outH,       // [T][B][NH]
    float* __restrict__ outY)       // [T][B][2]
{
    const int b = blockIdx.x;
    const int h = threadIdx.x;

    __shared__ float Hs[64][512];   // 128 KB history; col h private to thread h
    __shared__ float C[16][64];     // per-chunk coefficient matrix
    __shared__ float lam_pow[64];
    __shared__ float red[2][16];

    const float eta = etap[0];
    const float lam = fminf(lamp[0], 1.0f);
    const float2 w21v = *(const float2*)&w21[2 * h];
    const float2 w2v  = *(const float2*)&w2[2 * h];
    const float b20 = b2[0], b21 = b2[1];
    const float* gb  = Gt + (size_t)b * 4096;
    const float* Pb  = P + (size_t)b * NH + h;
    float*       oHb = outH + (size_t)b * NH + h;

    if (h < 64)
        lam_pow[h] = (h == 0) ? 1.0f : exp2f((float)h * log2f(lam));
    __syncthreads();   // order lam_pow writes before chunk-0 C-build reads

    float a2x = 0.f, a2y = 0.f;

    for (int c = 0; c < 4; ++c) {
        const int t0 = c * 16;

        // ---- build C cooperatively: 1024 entries, 2 per thread ----------
#pragma unroll
        for (int e = h; e < 1024; e += 512) {
            int tt = e >> 6, s = e & 63;
            int t  = t0 + tt;
            float cv = 0.f;
            if (s < t) cv = eta * lam_pow[t - 1 - s] * gb[t * 64 + s];
            C[tt][s] = cv;
        }
        __syncthreads();

        // ---- preload chunk's P (16 coalesced loads, covered by matmul) ---
        float pvreg[16];
#pragma unroll
        for (int tt = 0; tt < 16; ++tt)
            pvreg[tt] = Pb[(size_t)(t0 + tt) * (BATCH * NH)];

        // ---- past-chunk history matmul ----------------------------------
        float macc[16] = {};
#pragma unroll 2
        for (int s = 0; s < t0; ++s) {
            float hsv = Hs[s][h];
#pragma unroll
            for (int tt = 0; tt < 16; ++tt)
                macc[tt] = fmaf(C[tt][s], hsv, macc[tt]);
        }

        // ---- 16 sequential steps ----------------------------------------
        float hcur[16];
#pragma unroll
        for (int tt = 0; tt < 16; ++tt) {
            const int t   = t0 + tt;
            const int par = tt & 1;

            float a1 = pvreg[tt] + w21v.x * a2x + w21v.y * a2y + macc[tt];
#pragma unroll
            for (int j = 0; j < tt; ++j)
                a1 = fmaf(C[tt][t0 + j], hcur[j], a1);

            float hv = 1.0f / (1.0f + __expf(-a1));
            hcur[tt] = hv;
            Hs[t][h] = hv;
            oHb[(size_t)t * (BATCH * NH)] = hv;

            float p0 = dpp_sum64(hv * w2v.x);
            float p1 = dpp_sum64(hv * w2v.y);
            if ((h & 63) == 63) {
                red[par][(h >> 6) * 2]     = p0;
                red[par][(h >> 6) * 2 + 1] = p1;
            }
            __syncthreads();

            float4 r0 = *(const float4*)&red[par][0];
            float4 r1 = *(const float4*)&red[par][4];
            float4 r2 = *(const float4*)&red[par][8];
            float4 r3 = *(const float4*)&red[par][12];
            float s0 = b20 + ((r0.x + r0.z) + (r1.x + r1.z)) + ((r2.x + r2.z) + (r3.x + r3.z));
            float s1 = b21 + ((r0.y + r0.w) + (r1.y + r1.w)) + ((r2.y + r2.w) + (r3.y + r3.w));
            if (h == 0) {
                outY[((size_t)t * BATCH + b) * 2 + 0] = 1.0f / (1.0f + __expf(-s0));
                outY[((size_t)t * BATCH + b) * 2 + 1] = 1.0f / (1.0f + __expf(-s1));
            }
            a2x = s0; a2y = s1;
        }
    }
}

// ---------------------------------------------------------------------------
extern "C" void kernel_launch(void* const* d_in, const int* in_sizes, int n_in,
                              void* d_out, int out_size, void* d_ws, size_t ws_size,
                              hipStream_t stream) {
    const float* x   = (const float*)d_in[0];
    const float* w1  = (const float*)d_in[1];
    const float* b1  = (const float*)d_in[2];
    const float* w2  = (const float*)d_in[3];
    const float* b2  = (const float*)d_in[4];
    const float* w21 = (const float*)d_in[5];
    const float* lam = (const float*)d_in[6];
    const float* eta = (const float*)d_in[7];

    float* outH = (float*)d_out;                       // [64*256*512], doubles as P
    float* outY = outH + (size_t)T_STEPS * BATCH * NH; // [64*256*2]
    float* Gt   = (float*)d_ws;                        // [256*64*64] = 4 MB

    gemm_bf16_kernel<<<dim3(128, 4), 256, 0, stream>>>(x, w1, b1, outH);
    gram_kernel<<<256, 256, 0, stream>>>(x, Gt);
    scan_kernel<<<256, 512, 0, stream>>>(outH, Gt, w2, b2, w21, lam, eta, outH, outY);
}